// Round 1
// 4901.226 us; speedup vs baseline: 1.1214x; 1.1214x over previous
//
#include <hip/hip_runtime.h>
#include <hip/hip_bf16.h>

// ---------------------------------------------------------------------------
// RETRO-ish transformer forward, MI355X gfx950.
// Round 3: GEMM rewritten to m97-style bf16 gemm_bt:
//   - all weights pre-transposed + converted to bf16 (wtr_k) into a reused slot
//   - A operands bf16 (ln_k obf16 / gemm c_bf16 / f2bf_k)
//   - staging via global_load_lds width 16, chunk-linear LDS, ds_read_b128 frags
// Attention kernels unchanged (fp32 VALU flash). Workspace peak 68 MB.
//   B=2 S=1024 D=1024 H=16 DK=64 L=6 CL=64 V=32000 DFF=4096
//   CHUNKS=16 NEIGH=2 NLEN=128 CA_LAYER=3
// ---------------------------------------------------------------------------

#define MEG 1048576

using bf16x8 = __attribute__((ext_vector_type(8))) short;
using f32x4  = __attribute__((ext_vector_type(4))) float;

__device__ __forceinline__ unsigned short f2bf(float f) {
    unsigned int u = __float_as_uint(f);
    u += 0x7fffu + ((u >> 16) & 1u);          // round-to-nearest-even
    return (unsigned short)(u >> 16);
}
__device__ __forceinline__ float bf2f(unsigned short b) {
    return __uint_as_float((unsigned int)b << 16);
}

// async global->LDS, 16B per lane. LDS dest must be wave-uniform base + lane*16.
__device__ __forceinline__ void cp16(void* lds, const void* gmem) {
    __builtin_amdgcn_global_load_lds(
        (const __attribute__((address_space(1))) void*)gmem,
        (__attribute__((address_space(3))) void*)lds, 16, 0, 0);
}

// ---------------------------------------------------------------------------
// Embedding gather: h[row][:] = emb[x[row]][:]   (rows = B*S = 2048)
// ---------------------------------------------------------------------------
__global__ __launch_bounds__(256) void embed_k(const float* __restrict__ emb,
                                               const int* __restrict__ x,
                                               float* __restrict__ h) {
    int row = blockIdx.x;
    int d = threadIdx.x * 4;
    size_t src = (size_t)x[row] * 1024 + d;
    *(float4*)&h[(size_t)row * 1024 + d] = *(const float4*)&emb[src];
}

// ---------------------------------------------------------------------------
// fp32 -> bf16 bulk convert (2048x1024 rows for LM head A)
// ---------------------------------------------------------------------------
__global__ __launch_bounds__(256) void f2bf_k(const float* __restrict__ src,
                                              unsigned short* __restrict__ dst) {
    size_t i = ((size_t)blockIdx.x * 256 + threadIdx.x) * 4;
    float4 v = *(const float4*)&src[i];
    uint2 pk = { (unsigned)f2bf(v.x) | ((unsigned)f2bf(v.y) << 16),
                 (unsigned)f2bf(v.z) | ((unsigned)f2bf(v.w) << 16) };
    *(uint2*)&dst[i] = pk;
}

// ---------------------------------------------------------------------------
// Weight transpose + convert: Wt[n][k] = bf16(W[k][n]).  64x64 LDS tiles.
// grid (K/64, N/64) x 256 threads.
// ---------------------------------------------------------------------------
__global__ __launch_bounds__(256) void wtr_k(const float* __restrict__ W,
                                             unsigned short* __restrict__ Wt,
                                             int K, int N) {
    __shared__ float t[64][65];
    const int k0 = blockIdx.x * 64, n0 = blockIdx.y * 64;
    const int tid = threadIdx.x;
    #pragma unroll
    for (int e = 0; e < 16; e++) {
        int idx = e * 256 + tid;              // 0..4095
        int r = idx >> 6, c = idx & 63;       // r: k, c: n  (coalesced in n)
        t[r][c] = W[(size_t)(k0 + r) * N + n0 + c];
    }
    __syncthreads();
    #pragma unroll
    for (int e = 0; e < 8; e++) {
        int idx = e * 512 + tid * 2;          // 2 outputs/thread, coalesced in k
        int r = idx >> 6, c = idx & 63;       // r: n, c: k
        unsigned int pk = (unsigned)f2bf(t[c][r]) |
                          ((unsigned)f2bf(t[c + 1][r]) << 16);
        *(unsigned int*)&Wt[(size_t)(n0 + r) * K + k0 + c] = pk;
    }
}

// ---------------------------------------------------------------------------
// LayerNorm over D=1024. One block per row, 256 threads, 4 floats/thread.
// mode 0: dst[row] = LN(src[row])
// mode 1: dst[row] = LN(src[gidx[row]])          (gather, for ret_emb)
// mode 2: CCA prep: row=(b,r); r<961 -> LN(h[b][63+r]); else zeros
// obf16: write dst as bf16 (ushort) instead of fp32
// ---------------------------------------------------------------------------
__device__ __forceinline__ float block_sum(float v, float* red) {
    #pragma unroll
    for (int off = 32; off >= 1; off >>= 1) v += __shfl_xor(v, off);
    int w = threadIdx.x >> 6;
    __syncthreads();
    if ((threadIdx.x & 63) == 0) red[w] = v;
    __syncthreads();
    return red[0] + red[1] + red[2] + red[3];
}

__global__ __launch_bounds__(256) void ln_k(const float* __restrict__ src,
                                            void* __restrict__ dstv,
                                            const float* __restrict__ sc,
                                            const float* __restrict__ bi,
                                            const int* __restrict__ gidx,
                                            int mode, int obf16) {
    __shared__ float red[8];
    int row = blockIdx.x;
    int d = threadIdx.x * 4;
    const float* srow;
    if (mode == 0) {
        srow = src + (size_t)row * 1024;
    } else if (mode == 1) {
        srow = src + (size_t)gidx[row] * 1024;
    } else {
        int b = row >> 10, r = row & 1023;
        if (r >= 961) {                         // padded query rows -> zeros
            if (obf16) {
                uint2 z = {0u, 0u};
                *(uint2*)&((unsigned short*)dstv)[(size_t)row * 1024 + d] = z;
            } else {
                float4 z = {0.f, 0.f, 0.f, 0.f};
                *(float4*)&((float*)dstv)[(size_t)row * 1024 + d] = z;
            }
            return;
        }
        srow = src + (size_t)(b * 1024 + 63 + r) * 1024;
    }
    float4 xv = *(const float4*)&srow[d];
    float s = block_sum(xv.x + xv.y + xv.z + xv.w, red);
    float mu = s * (1.f / 1024.f);
    float d0 = xv.x - mu, d1 = xv.y - mu, d2 = xv.z - mu, d3 = xv.w - mu;
    float s2 = block_sum(d0*d0 + d1*d1 + d2*d2 + d3*d3, red);
    float rs = 1.0f / sqrtf(s2 * (1.f / 1024.f) + 1e-5f);
    float4 sv = *(const float4*)&sc[d];
    float4 bv = *(const float4*)&bi[d];
    float4 o = { d0*rs*sv.x + bv.x, d1*rs*sv.y + bv.y,
                 d2*rs*sv.z + bv.z, d3*rs*sv.w + bv.w };
    if (obf16) {
        uint2 pk = { (unsigned)f2bf(o.x) | ((unsigned)f2bf(o.y) << 16),
                     (unsigned)f2bf(o.z) | ((unsigned)f2bf(o.w) << 16) };
        *(uint2*)&((unsigned short*)dstv)[(size_t)row * 1024 + d] = pk;
    } else {
        *(float4*)&((float*)dstv)[(size_t)row * 1024 + d] = o;
    }
}

// ---------------------------------------------------------------------------
// bf16 MFMA GEMM (m97 structure): C[M,N] = A[M,K] @ Bt[N,K]^T + bias (+res)
// A bf16 row-major, Bt bf16 row-major (pre-transposed weight).
// Tile 128x128, BK=32, 4 waves (64x64 each), 4x4 16x16x32 frags.
// Staging: global_load_lds dwordx4, chunk-linear LDS [kc(4)][row(128)][8 bf16]
// so fragment reads are single ds_read_b128 and the wave-uniform+lane*16
// constraint of global_load_lds is satisfied (chunks consecutive per wave).
// grid.z selects among up to 3 (Bt,bias,C) triples (QKV batched in 1 launch).
// ---------------------------------------------------------------------------
struct GemmArgs {
    const unsigned short* A;
    const unsigned short* Bt[3];
    const float* bias[3];
    void*        C[3];
    const float* res;     // residual added to output (nullptr = none, fp32 only)
    int M, N, K;
    int relu, c_bf16;
};

__global__ __launch_bounds__(256) void gemm_k(GemmArgs g) {
    const int z = blockIdx.z;
    const unsigned short* __restrict__ A  = g.A;
    const unsigned short* __restrict__ Bt = g.Bt[z];
    const float* __restrict__ bias = g.bias[z];
    const int N = g.N, K = g.K;
    const int m0 = blockIdx.x * 128, n0 = blockIdx.y * 128;

    __shared__ __align__(16) short lA[4096];   // [kc][m][8] chunks, 8KB
    __shared__ __align__(16) short lB[4096];   // [kc][n][8] chunks, 8KB

    const int tid = threadIdx.x, wave = tid >> 6, lane = tid & 63;
    const int wm = (wave >> 1) * 64, wn = (wave & 1) * 64;

    f32x4 acc[4][4];
    f32x4 zero = {0.f, 0.f, 0.f, 0.f};
    #pragma unroll
    for (int i = 0; i < 4; i++)
        #pragma unroll
        for (int j = 0; j < 4; j++) acc[i][j] = zero;

    // per-thread chunk ids: j = i*256+tid; chunk j covers (kc=j>>7, row=j&127),
    // 16B = 8 bf16 at k-offset kc*8. Lanes of a wave are consecutive j ->
    // LDS dests are base + lane*16 as required by global_load_lds.
    for (int k0 = 0; k0 < K; k0 += 32) {
        __syncthreads();
        #pragma unroll
        for (int i = 0; i < 2; i++) {
            int j = i * 256 + tid;
            int kc = j >> 7, r = j & 127;
            cp16(&lA[j * 8], A  + (size_t)(m0 + r) * K + k0 + kc * 8);
            cp16(&lB[j * 8], Bt + (size_t)(n0 + r) * K + k0 + kc * 8);
        }
        __syncthreads();   // compiler drains vmcnt before barrier
        bf16x8 af[4], bfr[4];
        #pragma unroll
        for (int mi = 0; mi < 4; mi++)
            af[mi] = *(bf16x8*)&lA[((lane >> 4) * 128 + wm + mi * 16 + (lane & 15)) * 8];
        #pragma unroll
        for (int ni = 0; ni < 4; ni++)
            bfr[ni] = *(bf16x8*)&lB[((lane >> 4) * 128 + wn + ni * 16 + (lane & 15)) * 8];
        #pragma unroll
        for (int mi = 0; mi < 4; mi++)
            #pragma unroll
            for (int ni = 0; ni < 4; ni++)
                acc[mi][ni] = __builtin_amdgcn_mfma_f32_16x16x32_bf16(
                    af[mi], bfr[ni], acc[mi][ni], 0, 0, 0);
    }
    // ---- epilogue: C/D layout col=lane&15, row=(lane>>4)*4+r  (m89-verified)
    const int r0 = m0 + wm + (lane >> 4) * 4;
    const int c0 = n0 + wn + (lane & 15);
    #pragma unroll
    for (int ni = 0; ni < 4; ni++) {
        int col = c0 + ni * 16;
        float bb = bias[col];
        #pragma unroll
        for (int mi = 0; mi < 4; mi++) {
            #pragma unroll
            for (int r = 0; r < 4; r++) {
                int row = r0 + mi * 16 + r;
                float val = acc[mi][ni][r] + bb;
                if (g.relu) val = fmaxf(val, 0.f);
                if (g.c_bf16) {
                    ((unsigned short*)g.C[z])[(size_t)row * N + col] = f2bf(val);
                } else {
                    if (g.res) val += g.res[(size_t)row * N + col];
                    ((float*)g.C[z])[(size_t)row * N + col] = val;
                }
            }
        }
    }
}

// ---------------------------------------------------------------------------
// RoPE in-place on q and k. (B,S,H,DK) pairs (d, d+32), half=32.
// grid: (4096, 2) x 256 threads. blockIdx.y: 0 -> q, 1 -> k.
// ---------------------------------------------------------------------------
__global__ __launch_bounds__(256) void rope_k(float* __restrict__ q,
                                              float* __restrict__ k) {
    int idx = blockIdx.x * 256 + threadIdx.x;   // 0..1048575
    float* p = blockIdx.y ? k : q;
    int d    = idx & 31;
    int head = (idx >> 5) & 15;
    int i    = (idx >> 9) & 1023;
    int b    = idx >> 19;
    size_t base = ((size_t)(b * 1024 + i)) * 1024 + head * 64 + d;
    float x1 = p[base], x2 = p[base + 32];
    float th = __expf(-0.28782313662425575f * (float)d);  // ln(10000)/32
    float fr = (float)i * th;
    float s, c;
    sincosf(fr, &s, &c);
    p[base]      = x1 * c - x2 * s;
    p[base + 32] = x1 * s + x2 * c;
}

// ---------------------------------------------------------------------------
// Causal self-attention, flash-style, fp32 VALU. One block = (b,head, 64-query
// tile). 4 waves x 16 rows each. Keys streamed in 64-chunks with online
// softmax. K LDS is rotation-swizzled (slot j*64 + ((d+j)&63)) for
// conflict-free column reads. Output: h += softmax(QK^T/8) V   (residual).
// ---------------------------------------------------------------------------
__global__ __launch_bounds__(256) void attn_causal(const float* __restrict__ q,
                                                   const float* __restrict__ kk,
                                                   const float* __restrict__ vv,
                                                   float* __restrict__ h) {
    __shared__ __align__(16) float Qs[64 * 64];
    __shared__ __align__(16) float Ks[64 * 64];
    __shared__ __align__(16) float Vs[64 * 64];
    __shared__ __align__(16) float Ps[64 * 64];
    const int b = blockIdx.x >> 4, hd = blockIdx.x & 15, qt = blockIdx.y;
    const int tid = threadIdx.x, wave = tid >> 6, lane = tid & 63;
    const int w16 = wave * 16;
    const size_t qbase = ((size_t)(b * 1024 + qt * 64)) * 1024 + hd * 64;

    #pragma unroll
    for (int e = 0; e < 16; e++) {
        int elem = e * 256 + tid;
        int r = elem >> 6, d = elem & 63;
        Qs[r * 64 + d] = q[qbase + (size_t)r * 1024 + d] * 0.125f;
    }
    float acc[16], O[16], mrow[16], lrow[16];
    #pragma unroll
    for (int i = 0; i < 16; i++) { O[i] = 0.f; mrow[i] = -INFINITY; lrow[i] = 0.f; }

    for (int kt = 0; kt <= qt; kt++) {
        __syncthreads();
        size_t kbase = ((size_t)(b * 1024 + kt * 64)) * 1024 + hd * 64;
        #pragma unroll
        for (int e = 0; e < 16; e++) {
            int elem = e * 256 + tid;
            int r = elem >> 6, d = elem & 63;
            float kvv = kk[kbase + (size_t)r * 1024 + d];
            Ks[r * 64 + ((d + r) & 63)] = kvv;        // rotation swizzle
            Vs[r * 64 + d] = vv[kbase + (size_t)r * 1024 + d];
        }
        __syncthreads();
        // scores: lane = key j
        #pragma unroll
        for (int i = 0; i < 16; i++) acc[i] = 0.f;
        #pragma unroll 4
        for (int d4 = 0; d4 < 16; d4++) {
            float k0 = Ks[lane * 64 + ((4 * d4 + 0 + lane) & 63)];
            float k1 = Ks[lane * 64 + ((4 * d4 + 1 + lane) & 63)];
            float k2 = Ks[lane * 64 + ((4 * d4 + 2 + lane) & 63)];
            float k3 = Ks[lane * 64 + ((4 * d4 + 3 + lane) & 63)];
            #pragma unroll
            for (int rr = 0; rr < 16; rr++) {
                float4 qv = *(float4*)&Qs[(w16 + rr) * 64 + 4 * d4];
                acc[rr] += qv.x * k0 + qv.y * k1 + qv.z * k2 + qv.w * k3;
            }
        }
        // online softmax update
        bool diag = (kt == qt);
        #pragma unroll
        for (int rr = 0; rr < 16; rr++) {
            float s = acc[rr];
            if (diag && lane > (w16 + rr)) s = -INFINITY;
            float mx = s;
            #pragma unroll
            for (int off = 32; off >= 1; off >>= 1) mx = fmaxf(mx, __shfl_xor(mx, off));
            float mn = fmaxf(mrow[rr], mx);
            float alpha = __expf(mrow[rr] - mn);
            float pp = __expf(s - mn);
            float ps = pp;
            #pragma unroll
            for (int off = 32; off >= 1; off >>= 1) ps += __shfl_xor(ps, off);
            lrow[rr] = lrow[rr] * alpha + ps;
            mrow[rr] = mn;
            O[rr] *= alpha;
            Ps[(w16 + rr) * 64 + lane] = pp;          // wave-private rows
        }
        // PV: lane = dim d
        #pragma unroll 4
        for (int j4 = 0; j4 < 16; j4++) {
            float v0 = Vs[(4 * j4 + 0) * 64 + lane];
            float v1 = Vs[(4 * j4 + 1) * 64 + lane];
            float v2 = Vs[(4 * j4 + 2) * 64 + lane];
            float v3 = Vs[(4 * j4 + 3) * 64 + lane];
            #pragma unroll
            for (int rr = 0; rr < 16; rr++) {
                float4 pv = *(float4*)&Ps[(w16 + rr) * 64 + 4 * j4];
                O[rr] += pv.x * v0 + pv.y * v1 + pv.z * v2 + pv.w * v3;
            }
        }
    }
    #pragma unroll
    for (int rr = 0; rr < 16; rr++) {
        size_t idx = qbase + (size_t)(w16 + rr) * 1024 + lane;
        h[idx] += O[rr] / lrow[rr];                   // residual add
    }
}

// ---------------------------------------------------------------------------
// Chunked cross-attention core. block = (b*16+c, head). 64 queries (CL),
// 256 keys (NEIGH*NLEN) in 4 chunks, no mask. K/V in bf16. Output bf16
// (feeds the proj GEMM's A operand directly).
// ---------------------------------------------------------------------------
__global__ __launch_bounds__(256) void attn_cca(const float* __restrict__ q,
                                                const unsigned short* __restrict__ kk,
                                                const unsigned short* __restrict__ vv,
                                                unsigned short* __restrict__ out) {
    __shared__ __align__(16) float Qs[64 * 64];
    __shared__ __align__(16) float Ks[64 * 64];
    __shared__ __align__(16) float Vs[64 * 64];
    __shared__ __align__(16) float Ps[64 * 64];
    const int bc = blockIdx.x, hd = blockIdx.y;
    const int b = bc >> 4, c = bc & 15;
    const int tid = threadIdx.x, wave = tid >> 6, lane = tid & 63;
    const int w16 = wave * 16;
    const size_t qbase = ((size_t)(b * 1024 + c * 64)) * 1024 + hd * 64;
    const size_t kbase0 = ((size_t)(bc * 256)) * 1024 + hd * 64;

    #pragma unroll
    for (int e = 0; e < 16; e++) {
        int elem = e * 256 + tid;
        int r = elem >> 6, d = elem & 63;
        Qs[r * 64 + d] = q[qbase + (size_t)r * 1024 + d] * 0.125f;
    }
    float acc[16], O[16], mrow[16], lrow[16];
    #pragma unroll
    for (int i = 0; i < 16; i++) { O[i] = 0.f; mrow[i] = -INFINITY; lrow[i] = 0.f; }

    for (int kt = 0; kt < 4; kt++) {
        __syncthreads();
        size_t kbase = kbase0 + (size_t)(kt * 64) * 1024;
        #pragma unroll
        for (int e = 0; e < 16; e++) {
            int elem = e * 256 + tid;
            int r = elem >> 6, d = elem & 63;
            Ks[r * 64 + ((d + r) & 63)] = bf2f(kk[kbase + (size_t)r * 1024 + d]);
            Vs[r * 64 + d] = bf2f(vv[kbase + (size_t)r * 1024 + d]);
        }
        __syncthreads();
        #pragma unroll
        for (int i = 0; i < 16; i++) acc[i] = 0.f;
        #pragma unroll 4
        for (int d4 = 0; d4 < 16; d4++) {
            float k0 = Ks[lane * 64 + ((4 * d4 + 0 + lane) & 63)];
            float k1 = Ks[lane * 64 + ((4 * d4 + 1 + lane) & 63)];
            float k2 = Ks[lane * 64 + ((4 * d4 + 2 + lane) & 63)];
            float k3 = Ks[lane * 64 + ((4 * d4 + 3 + lane) & 63)];
            #pragma unroll
            for (int rr = 0; rr < 16; rr++) {
                float4 qv = *(float4*)&Qs[(w16 + rr) * 64 + 4 * d4];
                acc[rr] += qv.x * k0 + qv.y * k1 + qv.z * k2 + qv.w * k3;
            }
        }
        #pragma unroll
        for (int rr = 0; rr < 16; rr++) {
            float s = acc[rr];
            float mx = s;
            #pragma unroll
            for (int off = 32; off >= 1; off >>= 1) mx = fmaxf(mx, __shfl_xor(mx, off));
            float mn = fmaxf(mrow[rr], mx);
            float alpha = __expf(mrow[rr] - mn);
            float pp = __expf(s - mn);
            float ps = pp;
            #pragma unroll
            for (int off = 32; off >= 1; off >>= 1) ps += __shfl_xor(ps, off);
            lrow[rr] = lrow[rr] * alpha + ps;
            mrow[rr] = mn;
            O[rr] *= alpha;
            Ps[(w16 + rr) * 64 + lane] = pp;
        }
        #pragma unroll 4
        for (int j4 = 0; j4 < 16; j4++) {
            float v0 = Vs[(4 * j4 + 0) * 64 + lane];
            float v1 = Vs[(4 * j4 + 1) * 64 + lane];
            float v2 = Vs[(4 * j4 + 2) * 64 + lane];
            float v3 = Vs[(4 * j4 + 3) * 64 + lane];
            #pragma unroll
            for (int rr = 0; rr < 16; rr++) {
                float4 pv = *(float4*)&Ps[(w16 + rr) * 64 + 4 * j4];
                O[rr] += pv.x * v0 + pv.y * v1 + pv.z * v2 + pv.w * v3;
            }
        }
    }
    #pragma unroll
    for (int rr = 0; rr < 16; rr++) {
        size_t idx = qbase + (size_t)(w16 + rr) * 1024 + lane;
        out[idx] = f2bf(O[rr] / lrow[rr]);
    }
}

// ---------------------------------------------------------------------------
// CCA shift-add: h[b][63+r] += src[b][r] for r in 0..960
// ---------------------------------------------------------------------------
__global__ __launch_bounds__(256) void add_shift_k(const float* __restrict__ src,
                                                   float* __restrict__ h) {
    int row = blockIdx.x;              // 0..1921
    int b = row / 961, r = row % 961;
    int d = threadIdx.x * 4;
    size_t s = ((size_t)(b * 1024 + r)) * 1024 + d;
    size_t dst = ((size_t)(b * 1024 + 63 + r)) * 1024 + d;
    float4 a = *(const float4*)&src[s];
    float4 o = *(float4*)&h[dst];
    o.x += a.x; o.y += a.y; o.z += a.z; o.w += a.w;
    *(float4*)&h[dst] = o;
}

// ---------------------------------------------------------------------------
// Host orchestration
// ---------------------------------------------------------------------------
static void gemm(hipStream_t s, const unsigned short* A,
                 const unsigned short* B0, const unsigned short* B1,
                 const unsigned short* B2,
                 const float* bi0, const float* bi1, const float* bi2,
                 void* C0, void* C1, void* C2, const float* res,
                 int M, int N, int K, int relu, int c_bf16, int z) {
    GemmArgs ga;
    ga.A = A;
    ga.Bt[0] = B0; ga.Bt[1] = B1; ga.Bt[2] = B2;
    ga.bias[0] = bi0; ga.bias[1] = bi1; ga.bias[2] = bi2;
    ga.C[0] = C0; ga.C[1] = C1; ga.C[2] = C2;
    ga.res = res; ga.M = M; ga.N = N; ga.K = K;
    ga.relu = relu; ga.c_bf16 = c_bf16;
    gemm_k<<<dim3(M / 128, N / 128, z), 256, 0, s>>>(ga);
}

static void tr(hipStream_t s, const float* W, unsigned short* Wt, int K, int N) {
    wtr_k<<<dim3(K / 64, N / 64), 256, 0, s>>>(W, Wt, K, N);
}

extern "C" void kernel_launch(void* const* d_in, const int* in_sizes, int n_in,
                              void* d_out, int out_size, void* d_ws, size_t ws_size,
                              hipStream_t stream) {
    (void)in_sizes; (void)n_in; (void)out_size; (void)ws_size;
    const float* emb     = (const float*)d_in[0];
    const float* sa_ln_s = (const float*)d_in[1];
    const float* sa_ln_b = (const float*)d_in[2];
    const float* Wq      = (const float*)d_in[3];
    const float* Wk      = (const float*)d_in[4];
    const float* Wv      = (const float*)d_in[5];
    const float* bq      = (const float*)d_in[6];
    const float* bk      = (const float*)d_in[7];
    const float* bv      = (const float*)d_in[8];
    const float* ff_ln_s = (const float*)d_in[9];
    const float* ff_ln_b = (const float*)d_in[10];
    const float* W1      = (const float*)d_in[11];
    const float* b1      = (const float*)d_in[12];
    const float* W2      = (const float*)d_in[13];
    const float* b2      = (const float*)d_in[14];
    const float* cln_s   = (const float*)d_in[15];
    const float* cln_b   = (const float*)d_in[16];
    const float* cWq     = (const float*)d_in[17];
    const float* cWk     = (const float*)d_in[18];
    const float* cWv     = (const float*)d_in[19];
    const float* cbq     = (const float*)d_in[20];
    const float* cbk     = (const float*)d_in[21];
    const float* cbv     = (const float*)d_in[22];
    const float* cWo     = (const float*)d_in[23];
    const float* cbo     = (const float*)d_in[24];
    const float* ne_s    = (const float*)d_in[25];
    const float* ne_b    = (const float*)d_in[26];
    const float* Wr      = (const float*)d_in[27];
    const float* br      = (const float*)d_in[28];
    const int*   x       = (const int*)d_in[29];
    const int*   ret     = (const int*)d_in[30];
    float* out = (float*)d_out;
    float* ws  = (float*)d_ws;

    // -----------------------------------------------------------------------
    // Workspace layout (MB offsets; floats unless noted). PEAK = 68 MB.
    //   h     [ 0, 8)   residual stream (fp32)
    //   hn16  [ 8,12)   LN output bf16 (also CCA attn out bf16)
    //   qb    [12,20)   Q fp32            (CCA: q proj / proj out)
    //   kb    [20,28)   K fp32
    //   vb    [28,36)   V fp32
    //   ffh16 [36,52)   FFW hidden bf16
    //   wt    [60,68)   transposed-weight slot bf16 (QKV stacked / W1 / W2)
    //   CCA (layer 3 only, disjoint lifetimes):
    //     e16  bf16 [12,28)   LN(ret_emb) 8192x1024
    //     ck16 bf16 [28,44)   K_cca
    //     cv16 bf16 [44,60)   V_cca
    //   LM head (everything else dead):
    //     g16  bf16 [64,68)   bf16(h)
    //     wrt  bf16 [ 0,64)   Wr^T 32000x1024 (overwrites dead h)
    // -----------------------------------------------------------------------
    float*          h     = ws;
    unsigned short* hn16  = (unsigned short*)(ws + 2 * MEG);
    float*          qb    = ws + 3 * MEG;
    float*          kb    = ws + 5 * MEG;
    float*          vb    = ws + 7 * MEG;
    unsigned short* ffh16 = (unsigned short*)(ws + 9 * MEG);
    unsigned short* wt    = (unsigned short*)(ws + 15 * MEG);
    unsigned short* wt1   = wt + 1 * MEG;        // +2MB
    unsigned short* wt2   = wt + 2 * MEG;        // +4MB
    unsigned short* e16   = (unsigned short*)(ws + 3 * MEG);
    unsigned short* ck16  = (unsigned short*)(ws + 7 * MEG);
    unsigned short* cv16  = (unsigned short*)(ws + 11 * MEG);
    unsigned short* g16   = (unsigned short*)(ws + 16 * MEG);
    unsigned short* wrt   = (unsigned short*)ws;

    embed_k<<<2048, 256, 0, stream>>>(emb, x, h);

    for (int p = 0; p < 6; p++) {
        // ---- self attention ----
        ln_k<<<2048, 256, 0, stream>>>(h, hn16, sa_ln_s + p * 1024,
                                       sa_ln_b + p * 1024, nullptr, 0, 1);
        tr(stream, Wq + (size_t)p * MEG, wt,  1024, 1024);
        tr(stream, Wk + (size_t)p * MEG, wt1, 1024, 1024);
        tr(stream, Wv + (size_t)p * MEG, wt2, 1024, 1024);
        gemm(stream, hn16, wt, wt1, wt2,
             bq + p * 1024, bk + p * 1024, bv + p * 1024,
             qb, kb, vb, nullptr, 2048, 1024, 1024, 0, 0, 3);
        rope_k<<<dim3(4096, 2), 256, 0, stream>>>(qb, kb);
        attn_causal<<<dim3(32, 16), 256, 0, stream>>>(qb, kb, vb, h);

        // ---- chunked cross attention at layer 3 ----
        if (p == 3) {
            // e = LN(emb[ret]) -> bf16 (overwrites dead qb,kb)
            ln_k<<<8192, 256, 0, stream>>>(emb, e16, ne_s, ne_b, ret, 1, 1);
            tr(stream, cWk, wt,  1024, 1024);
            tr(stream, cWv, wt1, 1024, 1024);
            gemm(stream, e16, wt, wt1, wt1, cbk, cbv, cbv,
                 ck16, cv16, cv16, nullptr, 8192, 1024, 1024, 0, 1, 2);
            // e16 dead from here
            ln_k<<<2048, 256, 0, stream>>>(h, hn16, cln_s, cln_b, nullptr, 2, 1);
            tr(stream, cWq, wt, 1024, 1024);
            gemm(stream, hn16, wt, wt, wt, cbq, cbq, cbq,
                 qb, qb, qb, nullptr, 2048, 1024, 1024, 0, 0, 1);
            // attention out -> hn16 (bf16; hn16 free after q-gemm)
            attn_cca<<<dim3(32, 16), 256, 0, stream>>>(qb, ck16, cv16, hn16);
            tr(stream, cWo, wt, 1024, 1024);
            gemm(stream, hn16, wt, wt, wt, cbo, cbo, cbo,
                 qb, qb, qb, nullptr, 2048, 1024, 1024, 0, 0, 1);
            add_shift_k<<<1922, 256, 0, stream>>>(qb, h);
        }

        // ---- FFW ----
        ln_k<<<2048, 256, 0, stream>>>(h, hn16, ff_ln_s + p * 1024,
                                       ff_ln_b + p * 1024, nullptr, 0, 1);
        tr(stream, W1 + (size_t)p * 4 * MEG, wt, 1024, 4096);
        gemm(stream, hn16, wt, wt, wt,
             b1 + p * 4096, b1 + p * 4096, b1 + p * 4096,
             ffh16, ffh16, ffh16, nullptr, 2048, 4096, 1024, 1, 1, 1);
        tr(stream, W2 + (size_t)p * 4 * MEG, wt, 4096, 1024);
        gemm(stream, ffh16, wt, wt, wt,
             b2 + p * 1024, b2 + p * 1024, b2 + p * 1024,
             h, h, h, h /*residual*/, 2048, 1024, 4096, 0, 0, 1);
    }

    // ---- LM head: (2048 x 1024) @ (1024 x 32000) ----
    f2bf_k<<<2048, 256, 0, stream>>>(h, g16);       // h -> bf16
    tr(stream, Wr, wrt, 1024, 32000);               // Wr^T overwrites dead h
    gemm(stream, g16, wrt, wrt, wrt, br, br, br, out, out, out, nullptr,
         2048, 32000, 1024, 0, 0, 1);
}

// Round 2
// 2991.884 us; speedup vs baseline: 1.8370x; 1.6382x over previous
//
#include <hip/hip_runtime.h>
#include <hip/hip_bf16.h>

// ---------------------------------------------------------------------------
// RETRO-ish transformer forward, MI355X gfx950.
// Round 4: causal self-attention rewritten as bf16 MFMA flash attention.
//   - rope_k emits RoPE'd Q (x0.125) and K as bf16 in chunked MFMA layout
//   - vtr_k emits V^T chunked bf16
//   - attn_mfma: 64-q-tile / 4-wave flash kernel, K/V double-buffered via
//     global_load_lds, 16x16x32 bf16 MFMA for QK^T and PV, online softmax.
// GEMM path unchanged from round 3 (m97 structure, pre-transposed bf16 W).
//   B=2 S=1024 D=1024 H=16 DK=64 L=6 CL=64 V=32000 DFF=4096
//   CHUNKS=16 NEIGH=2 NLEN=128 CA_LAYER=3
// ---------------------------------------------------------------------------

#define MEG 1048576

using bf16x8 = __attribute__((ext_vector_type(8))) short;
using f32x4  = __attribute__((ext_vector_type(4))) float;

__device__ __forceinline__ unsigned short f2bf(float f) {
    unsigned int u = __float_as_uint(f);
    u += 0x7fffu + ((u >> 16) & 1u);          // round-to-nearest-even
    return (unsigned short)(u >> 16);
}
__device__ __forceinline__ float bf2f(unsigned short b) {
    return __uint_as_float((unsigned int)b << 16);
}

// async global->LDS, 16B per lane. LDS dest must be wave-uniform base + lane*16.
__device__ __forceinline__ void cp16(void* lds, const void* gmem) {
    __builtin_amdgcn_global_load_lds(
        (const __attribute__((address_space(1))) void*)gmem,
        (__attribute__((address_space(3))) void*)lds, 16, 0, 0);
}

// ---------------------------------------------------------------------------
// Embedding gather: h[row][:] = emb[x[row]][:]   (rows = B*S = 2048)
// ---------------------------------------------------------------------------
__global__ __launch_bounds__(256) void embed_k(const float* __restrict__ emb,
                                               const int* __restrict__ x,
                                               float* __restrict__ h) {
    int row = blockIdx.x;
    int d = threadIdx.x * 4;
    size_t src = (size_t)x[row] * 1024 + d;
    *(float4*)&h[(size_t)row * 1024 + d] = *(const float4*)&emb[src];
}

// ---------------------------------------------------------------------------
// fp32 -> bf16 bulk convert (2048x1024 rows for LM head A)
// ---------------------------------------------------------------------------
__global__ __launch_bounds__(256) void f2bf_k(const float* __restrict__ src,
                                              unsigned short* __restrict__ dst) {
    size_t i = ((size_t)blockIdx.x * 256 + threadIdx.x) * 4;
    float4 v = *(const float4*)&src[i];
    uint2 pk = { (unsigned)f2bf(v.x) | ((unsigned)f2bf(v.y) << 16),
                 (unsigned)f2bf(v.z) | ((unsigned)f2bf(v.w) << 16) };
    *(uint2*)&dst[i] = pk;
}

// ---------------------------------------------------------------------------
// Weight transpose + convert: Wt[n][k] = bf16(W[k][n]).  64x64 LDS tiles.
// grid (K/64, N/64) x 256 threads.
// ---------------------------------------------------------------------------
__global__ __launch_bounds__(256) void wtr_k(const float* __restrict__ W,
                                             unsigned short* __restrict__ Wt,
                                             int K, int N) {
    __shared__ float t[64][65];
    const int k0 = blockIdx.x * 64, n0 = blockIdx.y * 64;
    const int tid = threadIdx.x;
    #pragma unroll
    for (int e = 0; e < 16; e++) {
        int idx = e * 256 + tid;              // 0..4095
        int r = idx >> 6, c = idx & 63;       // r: k, c: n  (coalesced in n)
        t[r][c] = W[(size_t)(k0 + r) * N + n0 + c];
    }
    __syncthreads();
    #pragma unroll
    for (int e = 0; e < 8; e++) {
        int idx = e * 512 + tid * 2;          // 2 outputs/thread, coalesced in k
        int r = idx >> 6, c = idx & 63;       // r: n, c: k
        unsigned int pk = (unsigned)f2bf(t[c][r]) |
                          ((unsigned)f2bf(t[c + 1][r]) << 16);
        *(unsigned int*)&Wt[(size_t)(n0 + r) * K + k0 + c] = pk;
    }
}

// ---------------------------------------------------------------------------
// LayerNorm over D=1024. One block per row, 256 threads, 4 floats/thread.
// mode 0: dst[row] = LN(src[row])
// mode 1: dst[row] = LN(src[gidx[row]])          (gather, for ret_emb)
// mode 2: CCA prep: row=(b,r); r<961 -> LN(h[b][63+r]); else zeros
// obf16: write dst as bf16 (ushort) instead of fp32
// ---------------------------------------------------------------------------
__device__ __forceinline__ float block_sum(float v, float* red) {
    #pragma unroll
    for (int off = 32; off >= 1; off >>= 1) v += __shfl_xor(v, off);
    int w = threadIdx.x >> 6;
    __syncthreads();
    if ((threadIdx.x & 63) == 0) red[w] = v;
    __syncthreads();
    return red[0] + red[1] + red[2] + red[3];
}

__global__ __launch_bounds__(256) void ln_k(const float* __restrict__ src,
                                            void* __restrict__ dstv,
                                            const float* __restrict__ sc,
                                            const float* __restrict__ bi,
                                            const int* __restrict__ gidx,
                                            int mode, int obf16) {
    __shared__ float red[8];
    int row = blockIdx.x;
    int d = threadIdx.x * 4;
    const float* srow;
    if (mode == 0) {
        srow = src + (size_t)row * 1024;
    } else if (mode == 1) {
        srow = src + (size_t)gidx[row] * 1024;
    } else {
        int b = row >> 10, r = row & 1023;
        if (r >= 961) {                         // padded query rows -> zeros
            if (obf16) {
                uint2 z = {0u, 0u};
                *(uint2*)&((unsigned short*)dstv)[(size_t)row * 1024 + d] = z;
            } else {
                float4 z = {0.f, 0.f, 0.f, 0.f};
                *(float4*)&((float*)dstv)[(size_t)row * 1024 + d] = z;
            }
            return;
        }
        srow = src + (size_t)(b * 1024 + 63 + r) * 1024;
    }
    float4 xv = *(const float4*)&srow[d];
    float s = block_sum(xv.x + xv.y + xv.z + xv.w, red);
    float mu = s * (1.f / 1024.f);
    float d0 = xv.x - mu, d1 = xv.y - mu, d2 = xv.z - mu, d3 = xv.w - mu;
    float s2 = block_sum(d0*d0 + d1*d1 + d2*d2 + d3*d3, red);
    float rs = 1.0f / sqrtf(s2 * (1.f / 1024.f) + 1e-5f);
    float4 sv = *(const float4*)&sc[d];
    float4 bv = *(const float4*)&bi[d];
    float4 o = { d0*rs*sv.x + bv.x, d1*rs*sv.y + bv.y,
                 d2*rs*sv.z + bv.z, d3*rs*sv.w + bv.w };
    if (obf16) {
        uint2 pk = { (unsigned)f2bf(o.x) | ((unsigned)f2bf(o.y) << 16),
                     (unsigned)f2bf(o.z) | ((unsigned)f2bf(o.w) << 16) };
        *(uint2*)&((unsigned short*)dstv)[(size_t)row * 1024 + d] = pk;
    } else {
        *(float4*)&((float*)dstv)[(size_t)row * 1024 + d] = o;
    }
}

// ---------------------------------------------------------------------------
// bf16 MFMA GEMM (m97 structure): C[M,N] = A[M,K] @ Bt[N,K]^T + bias (+res)
// ---------------------------------------------------------------------------
struct GemmArgs {
    const unsigned short* A;
    const unsigned short* Bt[3];
    const float* bias[3];
    void*        C[3];
    const float* res;     // residual added to output (nullptr = none, fp32 only)
    int M, N, K;
    int relu, c_bf16;
};

__global__ __launch_bounds__(256) void gemm_k(GemmArgs g) {
    const int z = blockIdx.z;
    const unsigned short* __restrict__ A  = g.A;
    const unsigned short* __restrict__ Bt = g.Bt[z];
    const float* __restrict__ bias = g.bias[z];
    const int N = g.N, K = g.K;
    const int m0 = blockIdx.x * 128, n0 = blockIdx.y * 128;

    __shared__ __align__(16) short lA[4096];   // [kc][m][8] chunks, 8KB
    __shared__ __align__(16) short lB[4096];   // [kc][n][8] chunks, 8KB

    const int tid = threadIdx.x, wave = tid >> 6, lane = tid & 63;
    const int wm = (wave >> 1) * 64, wn = (wave & 1) * 64;

    f32x4 acc[4][4];
    f32x4 zero = {0.f, 0.f, 0.f, 0.f};
    #pragma unroll
    for (int i = 0; i < 4; i++)
        #pragma unroll
        for (int j = 0; j < 4; j++) acc[i][j] = zero;

    for (int k0 = 0; k0 < K; k0 += 32) {
        __syncthreads();
        #pragma unroll
        for (int i = 0; i < 2; i++) {
            int j = i * 256 + tid;
            int kc = j >> 7, r = j & 127;
            cp16(&lA[j * 8], A  + (size_t)(m0 + r) * K + k0 + kc * 8);
            cp16(&lB[j * 8], Bt + (size_t)(n0 + r) * K + k0 + kc * 8);
        }
        __syncthreads();   // compiler drains vmcnt before barrier
        bf16x8 af[4], bfr[4];
        #pragma unroll
        for (int mi = 0; mi < 4; mi++)
            af[mi] = *(bf16x8*)&lA[((lane >> 4) * 128 + wm + mi * 16 + (lane & 15)) * 8];
        #pragma unroll
        for (int ni = 0; ni < 4; ni++)
            bfr[ni] = *(bf16x8*)&lB[((lane >> 4) * 128 + wn + ni * 16 + (lane & 15)) * 8];
        #pragma unroll
        for (int mi = 0; mi < 4; mi++)
            #pragma unroll
            for (int ni = 0; ni < 4; ni++)
                acc[mi][ni] = __builtin_amdgcn_mfma_f32_16x16x32_bf16(
                    af[mi], bfr[ni], acc[mi][ni], 0, 0, 0);
    }
    // ---- epilogue: C/D layout col=lane&15, row=(lane>>4)*4+r  (m89-verified)
    const int r0 = m0 + wm + (lane >> 4) * 4;
    const int c0 = n0 + wn + (lane & 15);
    #pragma unroll
    for (int ni = 0; ni < 4; ni++) {
        int col = c0 + ni * 16;
        float bb = bias[col];
        #pragma unroll
        for (int mi = 0; mi < 4; mi++) {
            #pragma unroll
            for (int r = 0; r < 4; r++) {
                int row = r0 + mi * 16 + r;
                float val = acc[mi][ni][r] + bb;
                if (g.relu) val = fmaxf(val, 0.f);
                if (g.c_bf16) {
                    ((unsigned short*)g.C[z])[(size_t)row * N + col] = f2bf(val);
                } else {
                    if (g.res) val += g.res[(size_t)row * N + col];
                    ((float*)g.C[z])[(size_t)row * N + col] = val;
                }
            }
        }
    }
}

// ---------------------------------------------------------------------------
// RoPE: read fp32 q/k from GEMM, write RoPE'd bf16 in chunked MFMA layout:
//   dst[bh][dc(8)][i(1024)][j(8)]  (65536 ushorts per bh)
// Q additionally scaled by 0.125 (softmax 1/sqrt(DK) folded in).
// grid: (4096, 2) x 256. blockIdx.y: 0 -> q, 1 -> k.
// ---------------------------------------------------------------------------
__global__ __launch_bounds__(256) void rope_k(const float* __restrict__ q,
                                              const float* __restrict__ k,
                                              unsigned short* __restrict__ qc,
                                              unsigned short* __restrict__ kc) {
    int idx = blockIdx.x * 256 + threadIdx.x;   // 0..1048575
    const float* p = blockIdx.y ? k : q;
    unsigned short* pc = blockIdx.y ? kc : qc;
    float scale = blockIdx.y ? 1.0f : 0.125f;
    int d    = idx & 31;
    int head = (idx >> 5) & 15;
    int i    = (idx >> 9) & 1023;
    int b    = idx >> 19;
    size_t base = ((size_t)(b * 1024 + i)) * 1024 + head * 64 + d;
    float x1 = p[base], x2 = p[base + 32];
    float th = __expf(-0.28782313662425575f * (float)d);  // ln(10000)/32
    float fr = (float)i * th;
    float s, c;
    sincosf(fr, &s, &c);
    float o1 = (x1 * c - x2 * s) * scale;
    float o2 = (x1 * s + x2 * c) * scale;
    size_t hb = (size_t)(b * 16 + head) * 65536;
    pc[hb + ((size_t)(d >> 3) * 1024 + i) * 8 + (d & 7)]        = f2bf(o1);
    pc[hb + ((size_t)((d + 32) >> 3) * 1024 + i) * 8 + (d & 7)] = f2bf(o2);
}

// ---------------------------------------------------------------------------
// V transpose to chunked PV B-operand layout:
//   vc[bh][kc = i>>3 (128)][d(64)][j = i&7]    (65536 ushorts per bh)
// grid: 2048 x 256.
// ---------------------------------------------------------------------------
__global__ __launch_bounds__(256) void vtr_k(const float* __restrict__ v,
                                             unsigned short* __restrict__ vc) {
    int idx = blockIdx.x * 256 + threadIdx.x;   // 0..524287
    int d4  = idx & 15;
    int hh  = (idx >> 4) & 15;
    int tok = idx >> 8;                         // 0..2047
    int b = tok >> 10, i = tok & 1023;
    float4 x = *(const float4*)&v[(size_t)tok * 1024 + hh * 64 + d4 * 4];
    size_t base = (size_t)(b * 16 + hh) * 65536 +
                  ((size_t)(i >> 3) * 64 + d4 * 4) * 8 + (i & 7);
    vc[base]      = f2bf(x.x);
    vc[base + 8]  = f2bf(x.y);
    vc[base + 16] = f2bf(x.z);
    vc[base + 24] = f2bf(x.w);
}

// ---------------------------------------------------------------------------
// Causal flash attention, bf16 MFMA. Block = (bh, 64-query tile qt), 4 waves,
// wave owns 16 q rows. K/V 64-key tiles double-buffered via global_load_lds.
// Per k-tile per wave: 8 MFMA QK^T -> online softmax (C-layout registers,
// row-reduce via 4 shfl_xor in 16-lane group) -> P repack to A-frag layout
// through 2KB wave-private LDS -> 8 MFMA PV. Heavy tiles first (qt=15-y).
// Output: h += softmax(QK^T/8) V  (residual add).
// LDS 48KB -> 3 blocks/CU.
// ---------------------------------------------------------------------------
__global__ __launch_bounds__(256) void attn_mfma(
        const unsigned short* __restrict__ qc,
        const unsigned short* __restrict__ kcp,
        const unsigned short* __restrict__ vcp,
        float* __restrict__ h) {
    const int bh = blockIdx.x;                  // b*16 + head
    const int qt = 15 - (int)blockIdx.y;        // heavy q-tiles dispatch first
    const int b = bh >> 4, hd = bh & 15;
    const int tid = threadIdx.x, wave = tid >> 6, lane = tid & 63;
    const int li = lane & 15, lh = lane >> 4;

    __shared__ __align__(16) unsigned short Qs[4096];      // [dc8][q64][8]
    __shared__ __align__(16) unsigned short Ks[2][4096];   // [dc8][k64][8]
    __shared__ __align__(16) unsigned short Vs[2][4096];   // [kc8][d64][8]
    __shared__ __align__(16) unsigned short Ps[4][1024];   // per-wave [kc8][q16][8]

    const size_t hb = (size_t)bh * 65536;

    // stage Q (whole 64-row tile) + K/V tile 0
    #pragma unroll
    for (int i = 0; i < 2; i++) {
        int j = i * 256 + tid;
        cp16(&Qs[j * 8],    qc  + hb + ((size_t)(j >> 6) * 1024 + qt * 64 + (j & 63)) * 8);
        cp16(&Ks[0][j * 8], kcp + hb + ((size_t)(j >> 6) * 1024 + (j & 63)) * 8);
        cp16(&Vs[0][j * 8], vcp + hb + (size_t)j * 8);
    }
    __syncthreads();

    bf16x8 qf[2];
    #pragma unroll
    for (int c = 0; c < 2; c++)
        qf[c] = *(bf16x8*)&Qs[((c * 4 + lh) * 64 + wave * 16 + li) * 8];

    f32x4 Ot[4];
    f32x4 zero = {0.f, 0.f, 0.f, 0.f};
    #pragma unroll
    for (int t = 0; t < 4; t++) Ot[t] = zero;
    float mrow[4], lrow[4];
    #pragma unroll
    for (int r = 0; r < 4; r++) { mrow[r] = -3.0e38f; lrow[r] = 0.f; }

    int cur = 0;
    for (int kt = 0; kt <= qt; kt++) {
        if (kt < qt) {                          // prefetch next K/V tile
            #pragma unroll
            for (int i = 0; i < 2; i++) {
                int j = i * 256 + tid;
                cp16(&Ks[cur ^ 1][j * 8],
                     kcp + hb + ((size_t)(j >> 6) * 1024 + (kt + 1) * 64 + (j & 63)) * 8);
                cp16(&Vs[cur ^ 1][j * 8],
                     vcp + hb + ((size_t)(kt + 1) * 512 + j) * 8);
            }
        }
        // ---- QK^T: scores s[n] (16q x 16k per tile), fp32 accum
        f32x4 s[4];
        #pragma unroll
        for (int n = 0; n < 4; n++) s[n] = zero;
        #pragma unroll
        for (int c = 0; c < 2; c++) {
            #pragma unroll
            for (int n = 0; n < 4; n++) {
                bf16x8 kf = *(bf16x8*)&Ks[cur][((c * 4 + lh) * 64 + n * 16 + li) * 8];
                s[n] = __builtin_amdgcn_mfma_f32_16x16x32_bf16(qf[c], kf, s[n], 0, 0, 0);
            }
        }
        // ---- online softmax (row = q = wave*16 + lh*4 + r, col = n*16 + li)
        const bool diag = (kt == qt);
        float alpha[4];
        #pragma unroll
        for (int r = 0; r < 4; r++) {
            int qrow = wave * 16 + lh * 4 + r;  // within 64-q-tile
            float sv[4];
            float mx = -3.0e38f;
            #pragma unroll
            for (int n = 0; n < 4; n++) {
                float x = s[n][r];
                if (diag && (n * 16 + li) > qrow) x = -3.0e38f;
                sv[n] = x;
                mx = fmaxf(mx, x);
            }
            #pragma unroll
            for (int off = 8; off >= 1; off >>= 1) mx = fmaxf(mx, __shfl_xor(mx, off));
            float mn = fmaxf(mrow[r], mx);
            alpha[r] = __expf(mrow[r] - mn);
            float ps = 0.f;
            #pragma unroll
            for (int n = 0; n < 4; n++) {
                float p = __expf(sv[n] - mn);
                ps += p;
                // P repack: key = n*16+li -> [key>>3][q][key&7]
                Ps[wave][((n * 2 + (li >> 3)) * 16 + lh * 4 + r) * 8 + (lane & 7)] = f2bf(p);
            }
            #pragma unroll
            for (int off = 8; off >= 1; off >>= 1) ps += __shfl_xor(ps, off);
            lrow[r] = lrow[r] * alpha[r] + ps;
            mrow[r] = mn;
        }
        #pragma unroll
        for (int t = 0; t < 4; t++) {
            f32x4 o = Ot[t];
            o[0] *= alpha[0]; o[1] *= alpha[1]; o[2] *= alpha[2]; o[3] *= alpha[3];
            Ot[t] = o;
        }
        // ---- PV: Ot[t] += P(16q x 32k) @ V(32k x 16d)
        #pragma unroll
        for (int c = 0; c < 2; c++) {
            bf16x8 pf = *(bf16x8*)&Ps[wave][((c * 4 + lh) * 16 + li) * 8];
            #pragma unroll
            for (int t = 0; t < 4; t++) {
                bf16x8 vf = *(bf16x8*)&Vs[cur][((c * 4 + lh) * 64 + t * 16 + li) * 8];
                Ot[t] = __builtin_amdgcn_mfma_f32_16x16x32_bf16(pf, vf, Ot[t], 0, 0, 0);
            }
        }
        __syncthreads();                        // drains prefetch vmcnt, joins waves
        cur ^= 1;
    }
    // ---- epilogue: h += O / l   (row = q, col = d; C-layout)
    const size_t obase = ((size_t)(b * 1024 + qt * 64 + wave * 16 + lh * 4)) * 1024
                         + hd * 64 + li;
    #pragma unroll
    for (int r = 0; r < 4; r++) {
        float inv = 1.0f / lrow[r];
        #pragma unroll
        for (int t = 0; t < 4; t++) {
            size_t idx = obase + (size_t)r * 1024 + t * 16;
            h[idx] += Ot[t][r] * inv;
        }
    }
}

// ---------------------------------------------------------------------------
// Chunked cross-attention core (unchanged fp32 VALU path; single dispatch).
// block = (b*16+c, head). 64 queries, 256 keys in 4 chunks, no mask.
// K/V bf16 row-major. Output bf16 (feeds proj GEMM A directly).
// ---------------------------------------------------------------------------
__global__ __launch_bounds__(256) void attn_cca(const float* __restrict__ q,
                                                const unsigned short* __restrict__ kk,
                                                const unsigned short* __restrict__ vv,
                                                unsigned short* __restrict__ out) {
    __shared__ __align__(16) float Qs[64 * 64];
    __shared__ __align__(16) float Ks[64 * 64];
    __shared__ __align__(16) float Vs[64 * 64];
    __shared__ __align__(16) float Ps[64 * 64];
    const int bc = blockIdx.x, hd = blockIdx.y;
    const int b = bc >> 4, c = bc & 15;
    const int tid = threadIdx.x, wave = tid >> 6, lane = tid & 63;
    const int w16 = wave * 16;
    const size_t qbase = ((size_t)(b * 1024 + c * 64)) * 1024 + hd * 64;
    const size_t kbase0 = ((size_t)(bc * 256)) * 1024 + hd * 64;

    #pragma unroll
    for (int e = 0; e < 16; e++) {
        int elem = e * 256 + tid;
        int r = elem >> 6, d = elem & 63;
        Qs[r * 64 + d] = q[qbase + (size_t)r * 1024 + d] * 0.125f;
    }
    float acc[16], O[16], mrow[16], lrow[16];
    #pragma unroll
    for (int i = 0; i < 16; i++) { O[i] = 0.f; mrow[i] = -INFINITY; lrow[i] = 0.f; }

    for (int kt = 0; kt < 4; kt++) {
        __syncthreads();
        size_t kbase = kbase0 + (size_t)(kt * 64) * 1024;
        #pragma unroll
        for (int e = 0; e < 16; e++) {
            int elem = e * 256 + tid;
            int r = elem >> 6, d = elem & 63;
            Ks[r * 64 + ((d + r) & 63)] = bf2f(kk[kbase + (size_t)r * 1024 + d]);
            Vs[r * 64 + d] = bf2f(vv[kbase + (size_t)r * 1024 + d]);
        }
        __syncthreads();
        #pragma unroll
        for (int i = 0; i < 16; i++) acc[i] = 0.f;
        #pragma unroll 4
        for (int d4 = 0; d4 < 16; d4++) {
            float k0 = Ks[lane * 64 + ((4 * d4 + 0 + lane) & 63)];
            float k1 = Ks[lane * 64 + ((4 * d4 + 1 + lane) & 63)];
            float k2 = Ks[lane * 64 + ((4 * d4 + 2 + lane) & 63)];
            float k3 = Ks[lane * 64 + ((4 * d4 + 3 + lane) & 63)];
            #pragma unroll
            for (int rr = 0; rr < 16; rr++) {
                float4 qv = *(float4*)&Qs[(w16 + rr) * 64 + 4 * d4];
                acc[rr] += qv.x * k0 + qv.y * k1 + qv.z * k2 + qv.w * k3;
            }
        }
        #pragma unroll
        for (int rr = 0; rr < 16; rr++) {
            float s = acc[rr];
            float mx = s;
            #pragma unroll
            for (int off = 32; off >= 1; off >>= 1) mx = fmaxf(mx, __shfl_xor(mx, off));
            float mn = fmaxf(mrow[rr], mx);
            float alpha = __expf(mrow[rr] - mn);
            float pp = __expf(s - mn);
            float ps = pp;
            #pragma unroll
            for (int off = 32; off >= 1; off >>= 1) ps += __shfl_xor(ps, off);
            lrow[rr] = lrow[rr] * alpha + ps;
            mrow[rr] = mn;
            O[rr] *= alpha;
            Ps[(w16 + rr) * 64 + lane] = pp;
        }
        #pragma unroll 4
        for (int j4 = 0; j4 < 16; j4++) {
            float v0 = Vs[(4 * j4 + 0) * 64 + lane];
            float v1 = Vs[(4 * j4 + 1) * 64 + lane];
            float v2 = Vs[(4 * j4 + 2) * 64 + lane];
            float v3 = Vs[(4 * j4 + 3) * 64 + lane];
            #pragma unroll
            for (int rr = 0; rr < 16; rr++) {
                float4 pv = *(float4*)&Ps[(w16 + rr) * 64 + 4 * j4];
                O[rr] += pv.x * v0 + pv.y * v1 + pv.z * v2 + pv.w * v3;
            }
        }
    }
    #pragma unroll
    for (int rr = 0; rr < 16; rr++) {
        size_t idx = qbase + (size_t)(w16 + rr) * 1024 + lane;
        out[idx] = f2bf(O[rr] / lrow[rr]);
    }
}

// ---------------------------------------------------------------------------
// CCA shift-add: h[b][63+r] += src[b][r] for r in 0..960
// ---------------------------------------------------------------------------
__global__ __launch_bounds__(256) void add_shift_k(const float* __restrict__ src,
                                                   float* __restrict__ h) {
    int row = blockIdx.x;              // 0..1921
    int b = row / 961, r = row % 961;
    int d = threadIdx.x * 4;
    size_t s = ((size_t)(b * 1024 + r)) * 1024 + d;
    size_t dst = ((size_t)(b * 1024 + 63 + r)) * 1024 + d;
    float4 a = *(const float4*)&src[s];
    float4 o = *(float4*)&h[dst];
    o.x += a.x; o.y += a.y; o.z += a.z; o.w += a.w;
    *(float4*)&h[dst] = o;
}

// ---------------------------------------------------------------------------
// Host orchestration
// ---------------------------------------------------------------------------
static void gemm(hipStream_t s, const unsigned short* A,
                 const unsigned short* B0, const unsigned short* B1,
                 const unsigned short* B2,
                 const float* bi0, const float* bi1, const float* bi2,
                 void* C0, void* C1, void* C2, const float* res,
                 int M, int N, int K, int relu, int c_bf16, int z) {
    GemmArgs ga;
    ga.A = A;
    ga.Bt[0] = B0; ga.Bt[1] = B1; ga.Bt[2] = B2;
    ga.bias[0] = bi0; ga.bias[1] = bi1; ga.bias[2] = bi2;
    ga.C[0] = C0; ga.C[1] = C1; ga.C[2] = C2;
    ga.res = res; ga.M = M; ga.N = N; ga.K = K;
    ga.relu = relu; ga.c_bf16 = c_bf16;
    gemm_k<<<dim3(M / 128, N / 128, z), 256, 0, s>>>(ga);
}

static void tr(hipStream_t s, const float* W, unsigned short* Wt, int K, int N) {
    wtr_k<<<dim3(K / 64, N / 64), 256, 0, s>>>(W, Wt, K, N);
}

extern "C" void kernel_launch(void* const* d_in, const int* in_sizes, int n_in,
                              void* d_out, int out_size, void* d_ws, size_t ws_size,
                              hipStream_t stream) {
    (void)in_sizes; (void)n_in; (void)out_size; (void)ws_size;
    const float* emb     = (const float*)d_in[0];
    const float* sa_ln_s = (const float*)d_in[1];
    const float* sa_ln_b = (const float*)d_in[2];
    const float* Wq      = (const float*)d_in[3];
    const float* Wk      = (const float*)d_in[4];
    const float* Wv      = (const float*)d_in[5];
    const float* bq      = (const float*)d_in[6];
    const float* bk      = (const float*)d_in[7];
    const float* bv      = (const float*)d_in[8];
    const float* ff_ln_s = (const float*)d_in[9];
    const float* ff_ln_b = (const float*)d_in[10];
    const float* W1      = (const float*)d_in[11];
    const float* b1      = (const float*)d_in[12];
    const float* W2      = (const float*)d_in[13];
    const float* b2      = (const float*)d_in[14];
    const float* cln_s   = (const float*)d_in[15];
    const float* cln_b   = (const float*)d_in[16];
    const float* cWq     = (const float*)d_in[17];
    const float* cWk     = (const float*)d_in[18];
    const float* cWv     = (const float*)d_in[19];
    const float* cbq     = (const float*)d_in[20];
    const float* cbk     = (const float*)d_in[21];
    const float* cbv     = (const float*)d_in[22];
    const float* cWo     = (const float*)d_in[23];
    const float* cbo     = (const float*)d_in[24];
    const float* ne_s    = (const float*)d_in[25];
    const float* ne_b    = (const float*)d_in[26];
    const float* Wr      = (const float*)d_in[27];
    const float* br      = (const float*)d_in[28];
    const int*   x       = (const int*)d_in[29];
    const int*   ret     = (const int*)d_in[30];
    float* out = (float*)d_out;
    float* ws  = (float*)d_ws;

    // -----------------------------------------------------------------------
    // Workspace layout (MB offsets; floats unless noted). PEAK = 68 MB.
    //   h     [ 0, 8)   residual stream (fp32)
    //   hn16  [ 8,12)   LN output bf16 (also CCA attn out bf16)
    //   qb    [12,20)   Q fp32            (CCA: q proj / proj out)
    //   kb    [20,28)   K fp32
    //   vb    [28,36)   V fp32
    //   ffh16 [36,52)   FFW hidden bf16
    //     qc16 bf16 [36,40)  chunked RoPE'd Q   (attn only, pre-FFW)
    //     kc16 bf16 [40,44)  chunked RoPE'd K
    //     vc16 bf16 [44,48)  chunked V^T
    //   wt    [60,68)   transposed-weight slot bf16 (QKV stacked / W1 / W2)
    //   CCA (layer 3 only, disjoint lifetimes):
    //     e16  bf16 [12,28)   LN(ret_emb) 8192x1024
    //     ck16 bf16 [28,44)   K_cca
    //     cv16 bf16 [44,60)   V_cca
    //   LM head (everything else dead):
    //     g16  bf16 [64,68)   bf16(h)
    //     wrt  bf16 [ 0,64)   Wr^T 32000x1024 (overwrites dead h)
    // -----------------------------------------------------------------------
    float*          h     = ws;
    unsigned short* hn16  = (unsigned short*)(ws + 2 * MEG);
    float*          qb    = ws + 3 * MEG;
    float*          kb    = ws + 5 * MEG;
    float*          vb    = ws + 7 * MEG;
    unsigned short* ffh16 = (unsigned short*)(ws + 9 * MEG);
    unsigned short* qc16  = (unsigned short*)(ws + 9 * MEG);
    unsigned short* kc16  = (unsigned short*)(ws + 10 * MEG);
    unsigned short* vc16  = (unsigned short*)(ws + 11 * MEG);
    unsigned short* wt    = (unsigned short*)(ws + 15 * MEG);
    unsigned short* wt1   = wt + 1 * MEG;        // +2MB
    unsigned short* wt2   = wt + 2 * MEG;        // +4MB
    unsigned short* e16   = (unsigned short*)(ws + 3 * MEG);
    unsigned short* ck16  = (unsigned short*)(ws + 7 * MEG);
    unsigned short* cv16  = (unsigned short*)(ws + 11 * MEG);
    unsigned short* g16   = (unsigned short*)(ws + 16 * MEG);
    unsigned short* wrt   = (unsigned short*)ws;

    embed_k<<<2048, 256, 0, stream>>>(emb, x, h);

    for (int p = 0; p < 6; p++) {
        // ---- self attention ----
        ln_k<<<2048, 256, 0, stream>>>(h, hn16, sa_ln_s + p * 1024,
                                       sa_ln_b + p * 1024, nullptr, 0, 1);
        tr(stream, Wq + (size_t)p * MEG, wt,  1024, 1024);
        tr(stream, Wk + (size_t)p * MEG, wt1, 1024, 1024);
        tr(stream, Wv + (size_t)p * MEG, wt2, 1024, 1024);
        gemm(stream, hn16, wt, wt1, wt2,
             bq + p * 1024, bk + p * 1024, bv + p * 1024,
             qb, kb, vb, nullptr, 2048, 1024, 1024, 0, 0, 3);
        rope_k<<<dim3(4096, 2), 256, 0, stream>>>(qb, kb, qc16, kc16);
        vtr_k<<<2048, 256, 0, stream>>>(vb, vc16);
        attn_mfma<<<dim3(32, 16), 256, 0, stream>>>(qc16, kc16, vc16, h);

        // ---- chunked cross attention at layer 3 ----
        if (p == 3) {
            // e = LN(emb[ret]) -> bf16 (overwrites dead qb,kb)
            ln_k<<<8192, 256, 0, stream>>>(emb, e16, ne_s, ne_b, ret, 1, 1);
            tr(stream, cWk, wt,  1024, 1024);
            tr(stream, cWv, wt1, 1024, 1024);
            gemm(stream, e16, wt, wt1, wt1, cbk, cbv, cbv,
                 ck16, cv16, cv16, nullptr, 8192, 1024, 1024, 0, 1, 2);
            // e16 dead from here
            ln_k<<<2048, 256, 0, stream>>>(h, hn16, cln_s, cln_b, nullptr, 2, 1);
            tr(stream, cWq, wt, 1024, 1024);
            gemm(stream, hn16, wt, wt, wt, cbq, cbq, cbq,
                 qb, qb, qb, nullptr, 2048, 1024, 1024, 0, 0, 1);
            // attention out -> hn16 (bf16; hn16 free after q-gemm)
            attn_cca<<<dim3(32, 16), 256, 0, stream>>>(qb, ck16, cv16, hn16);
            tr(stream, cWo, wt, 1024, 1024);
            gemm(stream, hn16, wt, wt, wt, cbo, cbo, cbo,
                 qb, qb, qb, nullptr, 2048, 1024, 1024, 0, 0, 1);
            add_shift_k<<<1922, 256, 0, stream>>>(qb, h);
        }

        // ---- FFW ----
        ln_k<<<2048, 256, 0, stream>>>(h, hn16, ff_ln_s + p * 1024,
                                       ff_ln_b + p * 1024, nullptr, 0, 1);
        tr(stream, W1 + (size_t)p * 4 * MEG, wt, 1024, 4096);
        gemm(stream, hn16, wt, wt, wt,
             b1 + p * 4096, b1 + p * 4096, b1 + p * 4096,
             ffh16, ffh16, ffh16, nullptr, 2048, 4096, 1024, 1, 1, 1);
        tr(stream, W2 + (size_t)p * 4 * MEG, wt, 4096, 1024);
        gemm(stream, ffh16, wt, wt, wt,
             b2 + p * 1024, b2 + p * 1024, b2 + p * 1024,
             h, h, h, h /*residual*/, 2048, 1024, 4096, 0, 0, 1);
    }

    // ---- LM head: (2048 x 1024) @ (1024 x 32000) ----
    f2bf_k<<<2048, 256, 0, stream>>>(h, g16);       // h -> bf16
    tr(stream, Wr, wrt, 1024, 32000);               // Wr^T overwrites dead h
    gemm(stream, g16, wrt, wrt, wrt, br, br, br, out, out, out, nullptr,
         2048, 32000, 1024, 0, 0, 1);
}